// Round 6
// baseline (582.638 us; speedup 1.0000x reference)
//
#include <hip/hip_runtime.h>
#include <stdint.h>

#define E_NUM 8
#define H_DIM 1024
#define I_DIM 4096
#define N_TOK 2048
#define TOPK 2
#define NPAIR (N_TOK*TOPK)          // 4096
#define TM 128                       // slot padding granularity
#define MAXSLOT (NPAIR + E_NUM*TM)   // 5120
#define MAXTILE (MAXSLOT/TM)         // 40

typedef unsigned short u16;
typedef unsigned int u32;
typedef short short8 __attribute__((ext_vector_type(8)));   // 8 bf16 (4 VGPRs)
typedef float f32x4 __attribute__((ext_vector_type(4)));

// ---- workspace layout (bytes) ----
#define OFF_W1T  ((size_t)0)                  // [E][I][H] bf16 = 64 MiB
#define OFF_W3T  ((size_t)67108864)
#define OFF_W2T  ((size_t)134217728)          // [E][H][I] bf16 = 64 MiB
#define OFF_T    ((size_t)201326592)          // [MAXSLOT][I] bf16 = 40 MiB
#define OFF_Y    ((size_t)243269632)          // [MAXSLOT][H] bf16 = 10 MiB
#define OFF_XB   ((size_t)253755392)          // [N][H] bf16 = 4 MiB
#define OFF_META ((size_t)257949696)
// meta (int32 word indices):
#define M_TILES    0      // [0] = tiles_total
#define M_TEXP     8      // tile_expert[MAXTILE]
#define M_SLOTTOK  64     // slot_token[MAXSLOT]  (-1 = padding)
#define M_SLOTOF   5184   // slot_of_pair[NPAIR]
#define M_ZERO     9472   // zero page, 544 ints (covers zb+co+k0 reads)
#define M_ZERO_N   544

__device__ __forceinline__ float b2f(u16 h){ return __uint_as_float(((u32)h)<<16); }
__device__ __forceinline__ u16 f2b(float f){
  u32 u = __float_as_uint(f);
  u32 r = (u + 0x7FFFu + ((u>>16)&1u)) >> 16;   // RNE
  return (u16)r;
}
// async global->LDS, 16B per lane. LDS dest must be wave-uniform base + lane*16.
__device__ __forceinline__ void glds16(const void* g, void* l){
  __builtin_amdgcn_global_load_lds((const __attribute__((address_space(1))) void*)g,
                                   (__attribute__((address_space(3))) void*)l, 16, 0, 0);
}
// XOR bank swizzle: LDS chunk c (16B units, 8 chunks/row) holds global k-segment
// (c&7)^((c>>3)&7) of row c>>3. Reads of segment j, row r go to chunk r*8+(j^(r&7)).
__device__ __forceinline__ int swz_co(int chunk){   // global element offset of k-segment
  return (((chunk >> 3) ^ chunk) & 7) * 8;
}

// ---------------- fused preprocessing ----------------
// One launch: w1/w3/w2 transpose+downcast, x cast, routing sort.
// ROUND-2/3 LESSON: prep is LATENCY-bound (2.7 TB/s, VALUBusy 9%, nothing
// saturated). Compiler re-fuses split load/convert loops (VGPR stuck at 52,
// ~4 loads in flight/wave) -> can't raise ILP at source level.
// ROUND-5 FIX: raise TLP instead. 128x64 tile = 16.6 KB LDS -> 8 blocks/CU
// (32 waves, the cap) vs previous 128x128 (33 KB -> 4 blocks, 16 waves).
// 2x resident waves -> ~2x outstanding loads -> ~2x BW.
// Block map: [0,8192) w1/w3 tiles, [8192,12288) w2 tiles,
//            [12288,13312) castx, 13312 route.

__device__ __forceinline__ void tile_transpose64(const float* __restrict__ s,
                                                 u16* __restrict__ d,
                                                 int R, int C, int rb, int cb,
                                                 int tid, u16* tile){
  // fp32 [R][C] tile (rb..rb+128, cb..cb+64) -> bf16 [C][R].
  // LDS pitch 65 u16 (odd): readout column gathers land on distinct banks.
  float4 v[8];
  #pragma unroll
  for (int it = 0; it < 8; ++it){
    int idx = it*256 + tid;
    int row = idx >> 4, colq = (idx & 15) * 4;
    v[it] = *(const float4*)(s + (size_t)(rb+row)*C + cb + colq);
  }
  #pragma unroll
  for (int it = 0; it < 8; ++it){
    int idx = it*256 + tid;
    int row = idx >> 4, colq = (idx & 15) * 4;
    u16* p = &tile[row*65 + colq];
    p[0]=f2b(v[it].x); p[1]=f2b(v[it].y); p[2]=f2b(v[it].z); p[3]=f2b(v[it].w);
  }
  __syncthreads();
  #pragma unroll
  for (int it = 0; it < 4; ++it){
    int idx = it*256 + tid;
    int c = idx >> 4, rseg = (idx & 15) * 8;
    u16 o[8] __attribute__((aligned(16)));
    #pragma unroll
    for (int k = 0; k < 8; ++k) o[k] = tile[(rseg+k)*65 + c];
    *(uint4*)(void*)(d + (size_t)(cb+c)*R + rb + rseg) = *(const uint4*)(const void*)o;
  }
}

__global__ __launch_bounds__(256) void prep_kernel(
    const float* __restrict__ x, const int* __restrict__ ei,
    const float* __restrict__ w1, const float* __restrict__ w2,
    const float* __restrict__ w3,
    u16* __restrict__ xb, u16* __restrict__ w1t, u16* __restrict__ w2t,
    u16* __restrict__ w3t, int* __restrict__ meta)
{
  __shared__ u16 tile[128*65];
  __shared__ int cnt[E_NUM], base_s[E_NUM], cur[E_NUM];
  const int b = blockIdx.x;
  const int tid = threadIdx.x;

  if (b < 8192){
    // w1 (b<4096) / w3: [E][H=1024][I=4096] -> tiles 128 rows(H) x 64 cols(I)
    int which = b >> 12;
    int tt = b & 4095;
    int e  = tt >> 9;
    int t2 = tt & 511;
    int rb = (t2 >> 6) * 128;   // over R = H_DIM (8)
    int cb = (t2 & 63) * 64;    // over C = I_DIM (64)
    const float* s = (which ? w3 : w1) + (size_t)e * H_DIM * I_DIM;
    u16* d = (which ? w3t : w1t) + (size_t)e * H_DIM * I_DIM;
    tile_transpose64(s, d, H_DIM, I_DIM, rb, cb, tid, tile);
  } else if (b < 12288){
    // w2: [E][I=4096][H=1024] -> tiles 128 rows(I) x 64 cols(H)
    int tt = b - 8192;
    int e  = tt >> 9;
    int t2 = tt & 511;
    int rb = (t2 >> 4) * 128;   // over R = I_DIM (32)
    int cb = (t2 & 15) * 64;    // over C = H_DIM (16)
    const float* s = w2 + (size_t)e * H_DIM * I_DIM;
    u16* d = w2t + (size_t)e * H_DIM * I_DIM;
    tile_transpose64(s, d, I_DIM, H_DIM, rb, cb, tid, tile);
  } else if (b < 13312){
    // x cast: fp32 [N][H] -> bf16, 8 elems/thread
    int gid = (b - 12288) * 256 + tid;
    size_t base = (size_t)gid * 8;
    float4 a = *(const float4*)(x + base);
    float4 c = *(const float4*)(x + base + 4);
    u16 o[8] __attribute__((aligned(16)));
    o[0]=f2b(a.x); o[1]=f2b(a.y); o[2]=f2b(a.z); o[3]=f2b(a.w);
    o[4]=f2b(c.x); o[5]=f2b(c.y); o[6]=f2b(c.z); o[7]=f2b(c.w);
    *(uint4*)(void*)(xb + base) = *(const uint4*)(const void*)o;
  } else {
    // routing: counting sort of 4096 pairs by expert (single block)
    if (tid < E_NUM) cnt[tid] = 0;
    __syncthreads();
    for (int p = tid; p < NPAIR; p += 256) atomicAdd(&cnt[ei[p]], 1);
    __syncthreads();
    if (tid == 0){
      int run = 0, tl = 0;
      for (int e = 0; e < E_NUM; ++e){
        base_s[e] = run;
        int nt = (cnt[e] + TM - 1) / TM;
        for (int i = 0; i < nt; ++i) meta[M_TEXP + tl + i] = e;
        tl  += nt;
        run += nt * TM;
      }
      meta[M_TILES] = tl;
    }
    if (tid < E_NUM) cur[tid] = 0;
    for (int s = tid; s < MAXSLOT; s += 256) meta[M_SLOTTOK + s] = -1;
    for (int z = tid; z < M_ZERO_N; z += 256) meta[M_ZERO + z] = 0;
    __syncthreads();
    for (int p = tid; p < NPAIR; p += 256){
      int e = ei[p];
      int r = atomicAdd(&cur[e], 1);
      int slot = base_s[e] + r;
      meta[M_SLOTTOK + slot] = p >> 1;     // token id
      meta[M_SLOTOF + p] = slot;
    }
  }
}

// ---------------- phase 1: T[slot][i] = silu(x@W1) * (x@W3), grouped ----------------
// BM=128 slots x BN=64 i-cols, BK=64, 256 thr (4 waves, 2x2), dual accumulators.
// NOTE round-1 lesson: wider 128x128 tile (160 VGPR, 48KB LDS) drops occupancy
// 5->3 blocks/CU and with K=1024 (16 iters) the prologue/tail dominate: 477 TF
// vs this config's 614 TF. Keep many small high-occupancy blocks.
__global__ __launch_bounds__(256) void ffn1_kernel(
    const u16* __restrict__ x, const u16* __restrict__ w1t, const u16* __restrict__ w3t,
    u16* __restrict__ T, const int* __restrict__ meta)
{
  const int tiles = meta[M_TILES];
  const int mt_i = blockIdx.y;
  if (mt_i >= tiles) return;
  const int e = meta[M_TEXP + mt_i];
  const int slot0 = mt_i * 128;
  const int i0 = blockIdx.x * 64;

  __shared__ u16 sA[128*64];
  __shared__ u16 sB1[64*64];
  __shared__ u16 sB3[64*64];

  const int t = threadIdx.x;
  const int lane = t & 63;
  const int wave = t >> 6;
  const int m0 = (wave >> 1) * 64;
  const int n0 = (wave & 1) * 32;
  const int lr = lane & 15;
  const int lq = lane >> 4;          // 0..3

  const u16* zb = (const u16*)(meta + M_ZERO);
  const u16* abase[4]; u16* aldst[4];
  #pragma unroll
  for (int r = 0; r < 4; ++r){
    int chunk = r*256 + t;              // 1024 chunks of 16B cover 128x64 bf16
    int row = chunk >> 3;
    int co  = swz_co(chunk);            // swizzled k-segment
    int tok = meta[M_SLOTTOK + slot0 + row];
    abase[r] = (tok >= 0) ? (x + (size_t)tok*H_DIM + co) : (zb + co);
    aldst[r] = sA + chunk*8;
  }
  const u16* b1base[2]; const u16* b3base[2]; u16* b1dst[2]; u16* b3dst[2];
  #pragma unroll
  for (int r = 0; r < 2; ++r){
    int chunk = r*256 + t;              // 512 chunks cover 64x64 bf16
    int n  = chunk >> 3;
    int co = swz_co(chunk);
    size_t gb = ((size_t)e*I_DIM + i0 + n)*H_DIM + co;  // w1t/w3t: [E][I][H], k-contig
    b1base[r] = w1t + gb;  b3base[r] = w3t + gb;
    b1dst[r] = sB1 + chunk*8;  b3dst[r] = sB3 + chunk*8;
  }

  f32x4 zero4 = {0.f,0.f,0.f,0.f};
  f32x4 accG[4][2], accU[4][2];
  #pragma unroll
  for (int a = 0; a < 4; ++a){
    accG[a][0]=zero4; accG[a][1]=zero4; accU[a][0]=zero4; accU[a][1]=zero4;
  }

  for (int k0 = 0; k0 < H_DIM; k0 += 64){
    #pragma unroll
    for (int r = 0; r < 4; ++r) glds16(abase[r] + k0, aldst[r]);
    #pragma unroll
    for (int r = 0; r < 2; ++r){
      glds16(b1base[r] + k0, b1dst[r]);
      glds16(b3base[r] + k0, b3dst[r]);
    }
    __syncthreads();
    #pragma unroll
    for (int ks = 0; ks < 64; ks += 32){
      // k-segment index jj = ks/8 + lq; row r has its segment jj at chunk r*8+(jj^(r&7));
      // r&7 == lr&7 for all frags -> per-lane constant xor.
      const int sx = ((ks >> 3) + lq) ^ (lr & 7);
      short8 af[4];
      #pragma unroll
      for (int m = 0; m < 4; ++m)
        af[m] = *(const short8*)(const void*)(sA + (m0 + m*16 + lr)*64 + sx*8);
      #pragma unroll
      for (int n = 0; n < 2; ++n){
        short8 bg = *(const short8*)(const void*)(sB1 + (n0 + n*16 + lr)*64 + sx*8);
        short8 bu = *(const short8*)(const void*)(sB3 + (n0 + n*16 + lr)*64 + sx*8);
        #pragma unroll
        for (int m = 0; m < 4; ++m){
          accG[m][n] = __builtin_amdgcn_mfma_f32_16x16x32_bf16(af[m], bg, accG[m][n], 0,0,0);
          accU[m][n] = __builtin_amdgcn_mfma_f32_16x16x32_bf16(af[m], bu, accU[m][n], 0,0,0);
        }
      }
    }
    __syncthreads();
  }

  // epilogue: silu(gate)*up -> bf16. C/D layout: col=lane&15, row=(lane>>4)*4+r
  #pragma unroll
  for (int m = 0; m < 4; ++m)
  #pragma unroll
  for (int n = 0; n < 2; ++n)
  #pragma unroll
  for (int r = 0; r < 4; ++r){
    int row = m0 + m*16 + lq*4 + r;
    int col = i0 + n0 + n*16 + lr;
    float g = accG[m][n][r];
    float u = accU[m][n][r];
    float val = (g / (1.0f + __expf(-g))) * u;
    T[(size_t)(slot0 + row)*I_DIM + col] = f2b(val);
  }
}

// ---------------- phase 2: Y[slot][h] = T @ W2, grouped ----------------
__global__ __launch_bounds__(256) void ffn2_kernel(
    const u16* __restrict__ T, const u16* __restrict__ w2t,
    u16* __restrict__ Y, const int* __restrict__ meta)
{
  const int tiles = meta[M_TILES];
  const int mt_i = blockIdx.y;
  if (mt_i >= tiles) return;
  const int e = meta[M_TEXP + mt_i];
  const int slot0 = mt_i * 128;
  const int h0 = blockIdx.x * 64;

  __shared__ u16 sA[128*64];
  __shared__ u16 sB[64*64];

  const int t = threadIdx.x;
  const int lane = t & 63;
  const int wave = t >> 6;
  const int m0 = (wave >> 1) * 64;
  const int n0 = (wave & 1) * 32;
  const int lr = lane & 15;
  const int lq = lane >> 4;

  const u16* abase[4]; u16* aldst[4];
  #pragma unroll
  for (int r = 0; r < 4; ++r){
    int chunk = r*256 + t;
    int row = chunk >> 3;
    int co  = swz_co(chunk);
    abase[r] = T + (size_t)(slot0 + row)*I_DIM + co;   // pad rows of T are exact zeros
    aldst[r] = sA + chunk*8;
  }
  const u16* bbase[2]; u16* bdst[2];
  #pragma unroll
  for (int r = 0; r < 2; ++r){
    int chunk = r*256 + t;
    int n  = chunk >> 3;
    int co = swz_co(chunk);
    bbase[r] = w2t + ((size_t)e*H_DIM + h0 + n)*I_DIM + co;  // w2t: [E][H][I], k-contig
    bdst[r] = sB + chunk*8;
  }

  f32x4 zero4 = {0.f,0.f,0.f,0.f};
  f32x4 acc[4][2];
  #pragma unroll
  for (int a = 0; a < 4; ++a){ acc[a][0]=zero4; acc[a][1]=zero4; }

  for (int k0 = 0; k0 < I_DIM; k0 += 64){
    #pragma unroll
    for (int r = 0; r < 4; ++r) glds16(abase[r] + k0, aldst[r]);
    #pragma unroll
    for (int r = 0; r < 2; ++r) glds16(bbase[r] + k0, bdst[r]);
    __syncthreads();
    #pragma unroll
    for (int ks = 0; ks < 64; ks += 32){
      const int sx = ((ks >> 3) + lq) ^ (lr & 7);
      short8 af[4];
      #pragma unroll
      for (int m = 0; m < 4; ++m)
        af[m] = *(const short8*)(const void*)(sA + (m0 + m*16 + lr)*64 + sx*8);
      #pragma unroll
      for (int n = 0; n < 2; ++n){
        short8 bf = *(const short8*)(const void*)(sB + (n0 + n*16 + lr)*64 + sx*8);
        #pragma unroll
        for (int m = 0; m < 4; ++m)
          acc[m][n] = __builtin_amdgcn_mfma_f32_16x16x32_bf16(af[m], bf, acc[m][n], 0,0,0);
      }
    }
    __syncthreads();
  }

  #pragma unroll
  for (int m = 0; m < 4; ++m)
  #pragma unroll
  for (int n = 0; n < 2; ++n)
  #pragma unroll
  for (int r = 0; r < 4; ++r){
    int row = m0 + m*16 + lq*4 + r;
    int col = h0 + n0 + n*16 + lr;
    Y[(size_t)(slot0 + row)*H_DIM + col] = f2b(acc[m][n][r]);
  }
}

// ---------------- combine: out[n] = w0*Y[slot(n,0)] + w1*Y[slot(n,1)] ----------------
__global__ __launch_bounds__(256) void combine_kernel(
    const u16* __restrict__ Y, const float* __restrict__ ew,
    const int* __restrict__ meta, float* __restrict__ out)
{
  int gid = blockIdx.x * 256 + threadIdx.x;     // N*H/8 threads
  int n  = gid >> 7;
  int hc = (gid & 127) * 8;
  int s0 = meta[M_SLOTOF + n*2];
  int s1 = meta[M_SLOTOF + n*2 + 1];
  float w0 = ew[n*2];
  float w1v = ew[n*2 + 1];
  const short8 y0 = *(const short8*)(const void*)(Y + (size_t)s0*H_DIM + hc);
  const short8 y1 = *(const short8*)(const void*)(Y + (size_t)s1*H_DIM + hc);
  float o[8];
  #pragma unroll
  for (int j = 0; j < 8; ++j)
    o[j] = w0 * b2f((u16)y0[j]) + w1v * b2f((u16)y1[j]);
  float4* outv = (float4*)(out + (size_t)n*H_DIM + hc);
  outv[0] = *(float4*)(void*)&o[0];
  outv[1] = *(float4*)(void*)&o[4];
}

extern "C" void kernel_launch(void* const* d_in, const int* in_sizes, int n_in,
                              void* d_out, int out_size, void* d_ws, size_t ws_size,
                              hipStream_t stream)
{
  const float* x  = (const float*)d_in[0];
  const int*   ei = (const int*)d_in[1];
  const float* ew = (const float*)d_in[2];
  const float* w1 = (const float*)d_in[3];
  const float* w2 = (const float*)d_in[4];
  const float* w3 = (const float*)d_in[5];
  float* out = (float*)d_out;
  char* ws = (char*)d_ws;
  u16* w1t = (u16*)(ws + OFF_W1T);
  u16* w3t = (u16*)(ws + OFF_W3T);
  u16* w2t = (u16*)(ws + OFF_W2T);
  u16* Tb  = (u16*)(ws + OFF_T);
  u16* Yb  = (u16*)(ws + OFF_Y);
  u16* xb  = (u16*)(ws + OFF_XB);
  int* meta = (int*)(ws + OFF_META);

  prep_kernel<<<dim3(13313), 256, 0, stream>>>(x, ei, w1, w2, w3,
                                               xb, w1t, w2t, w3t, meta);
  ffn1_kernel<<<dim3(I_DIM/64, MAXTILE), 256, 0, stream>>>(xb, w1t, w3t, Tb, meta);
  ffn2_kernel<<<dim3(H_DIM/64, MAXTILE), 256, 0, stream>>>(Tb, w2t, Yb, meta);
  combine_kernel<<<dim3((N_TOK*H_DIM/8)/256), 256, 0, stream>>>(Yb, ew, meta, out);
}